// Round 1
// baseline (386.034 us; speedup 1.0000x reference)
//
#include <hip/hip_runtime.h>

// LNNRegression: fused 4-wave-specialized pipelined scan.
//   wave0: x prefetch (3-deep reg rotation) + FlashFloodGate h1 + pre_f/pre_s
//   wave1: cs/tau + fast&slow LTC recurrence (holds h state in regs)
//   wave2: fusion Linear(64->64)+tanh
//   wave3: attention a1/logit + online softmax accumulation
// Stage lags: load@i, x_sh write@i+2, gate t=i-3, rec t=i-4, fusion t=i-5, attn t=i-6.
// Depth-2 LDS rings; ONE raw barrier per step (lgkmcnt(0) only -> x loads stay in flight).
// Weights live in VGPRs (shared float w[64] per lane, role-dependent contents).

#define T_  512
#define D_  31
#define NIT 519   // 512 + 6 pipeline lag + pad to multiple of 3 (x-reg rotation)

__device__ __forceinline__ float fexp2(float x){ return __builtin_amdgcn_exp2f(x); }
__device__ __forceinline__ float frcp (float x){ return __builtin_amdgcn_rcpf(x); }
__device__ __forceinline__ float fast_tanh(float x){
    // tanh(x) = 1 - 2/(1+e^{2x}); saturates correctly at +-inf
    float e = fexp2(x * 2.8853900817779268f);
    return 1.0f - 2.0f * frcp(1.0f + e);
}
__device__ __forceinline__ float fast_sigmoid(float x){
    return frcp(1.0f + fexp2(x * -1.4426950408889634f));
}
#define L2E 1.4426950408889634f

// LDS-only barrier: do NOT use __syncthreads() (it drains vmcnt(0) and would
// stall wave0's x prefetch on HBM latency every step).
#define BAR() do { asm volatile("s_waitcnt lgkmcnt(0)" ::: "memory"); \
                   __builtin_amdgcn_s_barrier();                      \
                   asm volatile("" ::: "memory"); } while (0)

__launch_bounds__(256, 4)
__global__ void lnn_fused(
    const float* __restrict__ X,
    const float* __restrict__ fg_w1, const float* __restrict__ fg_b1,
    const float* __restrict__ fg_w2, const float* __restrict__ fg_b2,
    const float* __restrict__ fwin,  const float* __restrict__ fbin,
    const float* __restrict__ fwrec,
    const float* __restrict__ swin,  const float* __restrict__ sbin,
    const float* __restrict__ swrec,
    const float* __restrict__ fu_w,  const float* __restrict__ fu_b,
    const float* __restrict__ at_w1, const float* __restrict__ at_b1,
    const float* __restrict__ at_w2, const float* __restrict__ at_b2,
    const float* __restrict__ d_w1,  const float* __restrict__ d_b1,
    const float* __restrict__ d_w2,  const float* __restrict__ d_b2,
    const float* __restrict__ o_w1,  const float* __restrict__ o_b1,
    const float* __restrict__ o_w2,  const float* __restrict__ o_b2,
    const float* __restrict__ o_w3,  const float* __restrict__ o_b3,
    const float* __restrict__ i_w1,  const float* __restrict__ i_b1,
    const float* __restrict__ i_w2,  const float* __restrict__ i_b2,
    float* __restrict__ out, int B)
{
    const int b    = blockIdx.x;
    const int tx   = threadIdx.x;
    const int wid  = tx >> 6;
    const int lane = tx & 63;

    __shared__ float x_sh  [2][32];   // x_t (31 + zero pad)
    __shared__ float h1_sh [2][32];   // gate hidden
    __shared__ float pre_sh[2][64];   // pre_f(0:32) | pre_s(32:64)  (bias included)
    __shared__ float h_sh  [2][64];   // fast h | slow h
    __shared__ float ltc_sh[2][64];
    __shared__ float ctx_sh[64];

    if (tx < 128) ((float*)h_sh)[tx] = 0.0f;          // h_{-1} = 0
    if (tx == 0) { x_sh[0][31] = 0.0f; x_sh[1][31] = 0.0f; }

    // ---------------- per-wave weight preload into registers ----------------
    float w[64];
    float sA = 0.0f, sB = 0.0f, sC = 0.0f;
    if (wid == 0) {
        const int u = lane & 31;
        if (lane < 32) {
            // lanes 0-31: combined (A+B) gate row + fwin row
            #pragma unroll
            for (int j = 0; j < 31; ++j)
                w[j] = fg_w1[u*62 + j] + fg_w1[u*62 + 31 + j];
            w[31] = 0.0f;
            #pragma unroll
            for (int j = 0; j < 31; ++j) w[32+j] = fwin[u*31 + j];
            w[63] = 0.0f;
            sA = fg_b1[u];
            sB = fbin[u];
        } else {
            // lanes 32-63: B (dx) gate row -> produces y_t; swin row
            #pragma unroll
            for (int j = 0; j < 31; ++j) w[j] = fg_w1[u*62 + 31 + j];
            w[31] = 0.0f;
            #pragma unroll
            for (int j = 0; j < 31; ++j) w[32+j] = swin[u*31 + j];
            w[63] = 0.0f;
            sA = 0.0f;
            sB = sbin[u];
        }
    } else if (wid == 1) {
        const int u = lane & 31;
        const float* wr = (lane < 32) ? (fwrec + u*32) : (swrec + u*32);
        #pragma unroll
        for (int j = 0; j < 32; ++j) w[j] = wr[j];
        sA = fg_w2[u];
        sB = fg_b2[0];
    } else if (wid == 2) {
        #pragma unroll
        for (int j = 0; j < 64; ++j) w[j] = fu_w[lane*64 + j];
        sA = fu_b[lane];
    } else {
        const int r = lane & 31;
        #pragma unroll
        for (int j = 0; j < 32; ++j) w[j] = at_w1[r*64 + (lane & 32) + j];
        sA = at_b1[r];
        sB = at_w2[r];
        sC = at_b2[0];
    }

    // ---------------- pipeline state ----------------
    float y_prev = 0.0f;                 // wave0 (lanes<32): y_{t-1} = x_{t-1} @ B^T
    float h_st   = 0.0f;                 // wave1: own h unit
    float m_run  = -1.0e30f;             // wave3: online softmax
    float s_run  = 0.0f;
    float c_run  = 0.0f;                 // wave3: ctx accumulator (own ltc unit)
    float xpA = 0.0f, xpB = 0.0f, xpC = 0.0f;

    auto step = [&](int i, float& xld, float& xwr) {
        BAR();
        if (wid == 0) {
            // x prefetch: issue load for t=i (lands >=2 bodies later, counted vmcnt)
            if (i < T_ && lane < 31)
                xld = X[((size_t)b * T_ + i) * D_ + lane];
            // write x_{i-2} (loaded 2 bodies ago) to ring
            const int tw = i - 2;
            if (tw >= 0 && tw < T_ && lane < 31)
                x_sh[tw & 1][lane] = xwr;
            // gate + pre for t0 = i-3
            const int t0 = i - 3;
            if (t0 >= 0 && t0 < T_) {
                const int s = t0 & 1;
                float ag = 0.0f, ap = 0.0f;
                #pragma unroll
                for (int c = 0; c < 8; ++c) {
                    float4 xq = ((const float4*)(x_sh[s]))[c];
                    ag += w[4*c+0]*xq.x; ap += w[32+4*c+0]*xq.x;
                    ag += w[4*c+1]*xq.y; ap += w[32+4*c+1]*xq.y;
                    ag += w[4*c+2]*xq.z; ap += w[32+4*c+2]*xq.z;
                    ag += w[4*c+3]*xq.w; ap += w[32+4*c+3]*xq.w;
                }
                // lanes<32: ag = x@(A+B)^T ; lanes>=32: ag = y_t = x@B^T
                float yt   = __shfl_xor(ag, 32);
                float ycur = (t0 == 0) ? yt : y_prev;   // dx_0 = 0
                y_prev = yt;
                float h1 = fast_tanh(ag - ycur + sA);
                if (lane < 32) h1_sh[s][lane] = h1;
                pre_sh[s][lane] = ap + sB;
            }
        } else if (wid == 1) {
            const int t1 = i - 4;
            if (t1 >= 0 && t1 < T_) {
                const int s = t1 & 1;
                // cs -> tau (both halves compute identical reduction)
                float v = h1_sh[s][lane & 31] * sA;
                v += __shfl_xor(v, 1);  v += __shfl_xor(v, 2);
                v += __shfl_xor(v, 4);  v += __shfl_xor(v, 8);
                v += __shfl_xor(v, 16);
                float cs   = fast_sigmoid(v + sB);
                float tau  = 10.0f - 9.99f * cs;
                float rtau = (lane < 32) ? frcp(tau) : 0.2f;   // slow: 1/5
                // recurrence: upd = tanh(pre + Wrec @ h_prev)
                float acc = pre_sh[s][lane];
                const float4* hp = (const float4*)(h_sh[s ^ 1] + (lane & 32));
                #pragma unroll
                for (int c = 0; c < 8; ++c) {
                    float4 hq = hp[c];
                    acc += w[4*c+0]*hq.x + w[4*c+1]*hq.y
                         + w[4*c+2]*hq.z + w[4*c+3]*hq.w;
                }
                float upd = fast_tanh(acc);
                h_st += (upd - h_st) * rtau;
                h_sh[s][lane] = h_st;
            }
        } else if (wid == 2) {
            const int t2 = i - 5;
            if (t2 >= 0 && t2 < T_) {
                const int s = t2 & 1;
                float acc = sA;
                #pragma unroll
                for (int c = 0; c < 16; ++c) {
                    float4 hq = ((const float4*)h_sh[s])[c];
                    acc += w[4*c+0]*hq.x + w[4*c+1]*hq.y
                         + w[4*c+2]*hq.z + w[4*c+3]*hq.w;
                }
                ltc_sh[s][lane] = fast_tanh(acc);
            }
        } else {
            const int t3 = i - 6;
            if (t3 >= 0 && t3 < T_) {
                const int s = t3 & 1;
                float lt = ltc_sh[s][lane];
                const float4* lp = (const float4*)(ltc_sh[s] + (lane & 32));
                float acc = 0.0f;
                #pragma unroll
                for (int c = 0; c < 8; ++c) {
                    float4 lq = lp[c];
                    acc += w[4*c+0]*lq.x + w[4*c+1]*lq.y
                         + w[4*c+2]*lq.z + w[4*c+3]*lq.w;
                }
                acc += __shfl_xor(acc, 32);            // combine the two 32-halves
                float a1 = fast_tanh(acc + sA);
                float v  = a1 * sB;
                v += __shfl_xor(v, 1);  v += __shfl_xor(v, 2);
                v += __shfl_xor(v, 4);  v += __shfl_xor(v, 8);
                v += __shfl_xor(v, 16);
                float logit = v + sC;
                // online softmax
                float mn = fmaxf(m_run, logit);
                float e1 = fexp2((m_run - mn) * L2E);
                float p  = fexp2((logit - mn) * L2E);
                s_run = s_run * e1 + p;
                c_run = c_run * e1 + p * lt;
                m_run = mn;
            }
        }
    };

    for (int ii = 0; ii < NIT; ii += 3) {
        step(ii + 0, xpA, xpB);
        step(ii + 1, xpB, xpC);
        step(ii + 2, xpC, xpA);
    }

    // ---------------- epilogue: context + heads ----------------
    if (wid == 3) ctx_sh[lane] = c_run * frcp(s_run);
    BAR();

    if (wid == 0) {
        // depths head: Linear(64->64)+relu, Linear(64->5)
        float r1 = d_b1[lane];
        #pragma unroll
        for (int c = 0; c < 16; ++c) {
            float4 cq = ((const float4*)ctx_sh)[c];
            float4 wq = ((const float4*)(d_w1 + lane*64))[c];
            r1 += wq.x*cq.x + wq.y*cq.y + wq.z*cq.z + wq.w*cq.w;
        }
        r1 = fmaxf(r1, 0.0f);
        #pragma unroll
        for (int k = 0; k < 5; ++k) {
            float v = d_w2[k*64 + lane] * r1;
            v += __shfl_xor(v, 1);  v += __shfl_xor(v, 2);
            v += __shfl_xor(v, 4);  v += __shfl_xor(v, 8);
            v += __shfl_xor(v, 16); v += __shfl_xor(v, 32);
            if (lane == 0) out[b*5 + k] = v + d_b2[k];
        }
    } else if (wid == 1) {
        // overflow head: 64->64 relu, 64->32 relu, 32->1 sigmoid
        float r1 = o_b1[lane];
        #pragma unroll
        for (int c = 0; c < 16; ++c) {
            float4 cq = ((const float4*)ctx_sh)[c];
            float4 wq = ((const float4*)(o_w1 + lane*64))[c];
            r1 += wq.x*cq.x + wq.y*cq.y + wq.z*cq.z + wq.w*cq.w;
        }
        r1 = fmaxf(r1, 0.0f);
        const int r  = lane & 31;
        const int hb = lane & 32;
        float acc = 0.0f;
        #pragma unroll
        for (int j = 0; j < 32; ++j) {
            float rj = __shfl(r1, hb + j);
            acc += o_w2[r*64 + hb + j] * rj;
        }
        acc += __shfl_xor(acc, 32);
        float r2 = fmaxf(acc + o_b2[r], 0.0f);
        float v  = o_w3[r] * r2;
        v += __shfl_xor(v, 1);  v += __shfl_xor(v, 2);
        v += __shfl_xor(v, 4);  v += __shfl_xor(v, 8);
        v += __shfl_xor(v, 16);
        if (lane == 0) out[5*B + b] = fast_sigmoid(v + o_b3[0]);
    } else if (wid == 2) {
        // intensity head: 64->32 relu, 32->1 sigmoid
        const int r  = lane & 31;
        const int hb = lane & 32;
        float acc = 0.0f;
        #pragma unroll
        for (int c = 0; c < 8; ++c) {
            float4 cq = ((const float4*)(ctx_sh + hb))[c];
            float4 wq = ((const float4*)(i_w1 + r*64 + hb))[c];
            acc += wq.x*cq.x + wq.y*cq.y + wq.z*cq.z + wq.w*cq.w;
        }
        acc += __shfl_xor(acc, 32);
        float r1 = fmaxf(acc + i_b1[r], 0.0f);
        float v  = i_w2[r] * r1;
        v += __shfl_xor(v, 1);  v += __shfl_xor(v, 2);
        v += __shfl_xor(v, 4);  v += __shfl_xor(v, 8);
        v += __shfl_xor(v, 16);
        if (lane == 0) out[6*B + b] = fast_sigmoid(v + i_b2[0]);
    }
}

extern "C" void kernel_launch(void* const* d_in, const int* in_sizes, int n_in,
                              void* d_out, int out_size, void* d_ws, size_t ws_size,
                              hipStream_t stream) {
    (void)n_in; (void)out_size; (void)d_ws; (void)ws_size;
    const float* X     = (const float*)d_in[0];
    const float* fg_w1 = (const float*)d_in[1];
    const float* fg_b1 = (const float*)d_in[2];
    const float* fg_w2 = (const float*)d_in[3];
    const float* fg_b2 = (const float*)d_in[4];
    const float* fwin  = (const float*)d_in[5];
    const float* fbin  = (const float*)d_in[6];
    const float* fwrec = (const float*)d_in[7];
    const float* swin  = (const float*)d_in[8];
    const float* sbin  = (const float*)d_in[9];
    const float* swrec = (const float*)d_in[10];
    const float* fu_w  = (const float*)d_in[11];
    const float* fu_b  = (const float*)d_in[12];
    const float* at_w1 = (const float*)d_in[13];
    const float* at_b1 = (const float*)d_in[14];
    const float* at_w2 = (const float*)d_in[15];
    const float* at_b2 = (const float*)d_in[16];
    const float* d_w1  = (const float*)d_in[17];
    const float* d_b1  = (const float*)d_in[18];
    const float* d_w2  = (const float*)d_in[19];
    const float* d_b2  = (const float*)d_in[20];
    const float* o_w1  = (const float*)d_in[21];
    const float* o_b1  = (const float*)d_in[22];
    const float* o_w2  = (const float*)d_in[23];
    const float* o_b2  = (const float*)d_in[24];
    const float* o_w3  = (const float*)d_in[25];
    const float* o_b3  = (const float*)d_in[26];
    const float* i_w1  = (const float*)d_in[27];
    const float* i_b1  = (const float*)d_in[28];
    const float* i_w2  = (const float*)d_in[29];
    const float* i_b2  = (const float*)d_in[30];
    float* out = (float*)d_out;

    const int B = in_sizes[0] / (T_ * D_);
    dim3 grid(B), block(256);
    hipLaunchKernelGGL(lnn_fused, grid, block, 0, stream,
        X, fg_w1, fg_b1, fg_w2, fg_b2, fwin, fbin, fwrec, swin, sbin, swrec,
        fu_w, fu_b, at_w1, at_b1, at_w2, at_b2, d_w1, d_b1, d_w2, d_b2,
        o_w1, o_b1, o_w2, o_b2, o_w3, o_b3, i_w1, i_b1, i_w2, i_b2, out, B);
}

// Round 2
// 378.108 us; speedup vs baseline: 1.0210x; 1.0210x over previous
//
#include <hip/hip_runtime.h>

// LNNRegression: fused 4-wave-specialized pipelined scan (role-split loops).
//   wave0: x DMA prefetch (global_load_lds, depth-4 ring, counted vmcnt(3))
//          + FlashFloodGate hidden + pre_f/pre_s
//   wave1: cs/tau + fast&slow LTC recurrence (h state in regs)
//   wave2: fusion Linear(64->64)+tanh (lane-split dot, half LDS reads)
//   wave3: attention + online softmax accumulation
// Lags: DMA t=i, gate t=i-3, rec t=i-4, fusion t=i-5, attn t=i-6. NIT=518.
// Depth-2 LDS rings for h1/pre/h/ltc; ONE raw barrier (lgkmcnt only) per step.
// All weights in role-local, constant-indexed register arrays (no lambdas —
// round-1's lambda blocked SROA: VGPR=64 + 32GB scratch FETCH).

#define T_  512
#define D_  31
#define NIT 518   // 512 + 6 pipeline lag

__device__ __forceinline__ float fexp2(float x){ return __builtin_amdgcn_exp2f(x); }
__device__ __forceinline__ float frcp (float x){ return __builtin_amdgcn_rcpf(x); }
__device__ __forceinline__ float fast_tanh(float x){
    float e = fexp2(x * 2.8853900817779268f);
    return 1.0f - 2.0f * frcp(1.0f + e);
}
__device__ __forceinline__ float fast_sigmoid(float x){
    return frcp(1.0f + fexp2(x * -1.4426950408889634f));
}
#define L2E 1.4426950408889634f

// LDS-only barrier: raw s_barrier with lgkmcnt drain only. Never vmcnt(0) in
// the main loop -> DMA x-prefetch stays in flight across barriers.
#define BAR() do { asm volatile("s_waitcnt lgkmcnt(0)" ::: "memory"); \
                   __builtin_amdgcn_s_barrier();                      \
                   asm volatile("" ::: "memory"); } while (0)

__launch_bounds__(256, 4)
__global__ void lnn_fused(
    const float* __restrict__ X,
    const float* __restrict__ fg_w1, const float* __restrict__ fg_b1,
    const float* __restrict__ fg_w2, const float* __restrict__ fg_b2,
    const float* __restrict__ fwin,  const float* __restrict__ fbin,
    const float* __restrict__ fwrec,
    const float* __restrict__ swin,  const float* __restrict__ sbin,
    const float* __restrict__ swrec,
    const float* __restrict__ fu_w,  const float* __restrict__ fu_b,
    const float* __restrict__ at_w1, const float* __restrict__ at_b1,
    const float* __restrict__ at_w2, const float* __restrict__ at_b2,
    const float* __restrict__ d_w1,  const float* __restrict__ d_b1,
    const float* __restrict__ d_w2,  const float* __restrict__ d_b2,
    const float* __restrict__ o_w1,  const float* __restrict__ o_b1,
    const float* __restrict__ o_w2,  const float* __restrict__ o_b2,
    const float* __restrict__ o_w3,  const float* __restrict__ o_b3,
    const float* __restrict__ i_w1,  const float* __restrict__ i_b1,
    const float* __restrict__ i_w2,  const float* __restrict__ i_b2,
    float* __restrict__ out, int B)
{
    const int b    = blockIdx.x;
    const int tx   = threadIdx.x;
    const int wid  = tx >> 6;
    const int lane = tx & 63;

    __shared__ float x_sh  [4][32];   // DMA ring: x_t (31 + zero pad)
    __shared__ float h1_sh [2][32];   // gate hidden
    __shared__ float pre_sh[2][64];   // pre_f(0:32) | pre_s(32:64) (bias incl.)
    __shared__ float h_sh  [2][64];   // fast h | slow h
    __shared__ float ltc_sh[2][64];
    __shared__ float ctx_sh[64];

    if (tx < 128) ((float*)h_sh)[tx] = 0.0f;                       // h_{-1}=0
    if (tx < 4)   x_sh[tx][31] = 0.0f;                             // pads

    if (wid == 0) {
        // ================= role 0: x DMA + gate + pre =================
        float w[64];                    // gate row (0:32) | win row (32:64)
        float sA, sB;
        const int u = lane & 31;
        if (lane < 32) {
            #pragma unroll
            for (int j = 0; j < 31; ++j)
                w[j] = fg_w1[u*62 + j] + fg_w1[u*62 + 31 + j];     // (A+B) row
            w[31] = 0.0f;
            #pragma unroll
            for (int j = 0; j < 31; ++j) w[32+j] = fwin[u*31 + j];
            w[63] = 0.0f;
            sA = fg_b1[u]; sB = fbin[u];
        } else {
            #pragma unroll
            for (int j = 0; j < 31; ++j) w[j] = fg_w1[u*62 + 31 + j]; // B row -> y
            w[31] = 0.0f;
            #pragma unroll
            for (int j = 0; j < 31; ++j) w[32+j] = swin[u*31 + j];
            w[63] = 0.0f;
            sA = 0.0f; sB = sbin[u];
        }
        const float* xsrc = X + (size_t)b * T_ * D_ + lane;
        float y_prev = 0.0f;
        // drain weight preloads so manual vmcnt counting starts clean
        asm volatile("s_waitcnt vmcnt(0)" ::: "memory");

        for (int i = 0; i < NIT; ++i) {
            BAR();
            // DMA x_t -> x_sh[i&3] (clamped dummy for i>=T keeps count uniform)
            if (lane < D_)
                __builtin_amdgcn_global_load_lds(
                    (const __attribute__((address_space(1))) unsigned int*)xsrc,
                    (__attribute__((address_space(3))) unsigned int*)(&x_sh[i & 3][0]),
                    4, 0, 0);
            if (i < T_ - 1) xsrc += D_;

            const int t0 = i - 3;
            if (t0 >= 0 && t0 < T_) {
                asm volatile("s_waitcnt vmcnt(3)" ::: "memory");   // load t0 landed
                __builtin_amdgcn_sched_barrier(0);
                const int s = t0 & 1;
                const float4* xq4 = (const float4*)(&x_sh[t0 & 3][0]);
                float ag = 0.0f, ap = 0.0f;
                #pragma unroll
                for (int c = 0; c < 8; ++c) {
                    float4 xq = xq4[c];
                    ag += w[4*c+0]*xq.x; ap += w[32+4*c+0]*xq.x;
                    ag += w[4*c+1]*xq.y; ap += w[32+4*c+1]*xq.y;
                    ag += w[4*c+2]*xq.z; ap += w[32+4*c+2]*xq.z;
                    ag += w[4*c+3]*xq.w; ap += w[32+4*c+3]*xq.w;
                }
                float yt   = __shfl_xor(ag, 32);        // lanes<32 get y_t
                float ycur = (t0 == 0) ? yt : y_prev;   // dx_0 = 0
                y_prev = yt;
                float h1 = fast_tanh(ag - ycur + sA);
                if (lane < 32) h1_sh[s][lane] = h1;
                pre_sh[s][lane] = ap + sB;
            }
        }
    } else if (wid == 1) {
        // ================= role 1: tau + LTC recurrence =================
        float w[32];
        const int u = lane & 31;
        const float* wr = (lane < 32) ? (fwrec + u*32) : (swrec + u*32);
        #pragma unroll
        for (int j = 0; j < 32; ++j) w[j] = wr[j];
        const float sA = fg_w2[u];
        const float sB = fg_b2[0];
        float h_st = 0.0f;

        for (int i = 0; i < NIT; ++i) {
            BAR();
            const int t1 = i - 4;
            if (t1 >= 0 && t1 < T_) {
                const int s = t1 & 1;
                float v = h1_sh[s][u] * sA;
                v += __shfl_xor(v, 1);  v += __shfl_xor(v, 2);
                v += __shfl_xor(v, 4);  v += __shfl_xor(v, 8);
                v += __shfl_xor(v, 16);
                float cs   = fast_sigmoid(v + sB);
                float rtau = (lane < 32) ? frcp(10.0f - 9.99f * cs) : 0.2f;
                float acc = pre_sh[s][lane];
                const float4* hp = (const float4*)(h_sh[s ^ 1] + (lane & 32));
                #pragma unroll
                for (int c = 0; c < 8; ++c) {
                    float4 hq = hp[c];
                    acc += w[4*c+0]*hq.x + w[4*c+1]*hq.y
                         + w[4*c+2]*hq.z + w[4*c+3]*hq.w;
                }
                float upd = fast_tanh(acc);
                h_st += (upd - h_st) * rtau;
                h_sh[s][lane] = h_st;
            }
        }
    } else if (wid == 2) {
        // ================= role 2: fusion (lane-split dot) =================
        float wa[32], wb[32];
        const int r  = lane & 31;
        const int hb = lane & 32;
        #pragma unroll
        for (int j = 0; j < 32; ++j) {
            wa[j] = fu_w[ r      *64 + hb + j];
            wb[j] = fu_w[(r + 32)*64 + hb + j];
        }
        const float sA = fu_b[lane];

        for (int i = 0; i < NIT; ++i) {
            BAR();
            const int t2 = i - 5;
            if (t2 >= 0 && t2 < T_) {
                const int s = t2 & 1;
                const float4* hp = (const float4*)(h_sh[s] + hb);
                float a = 0.0f, bb = 0.0f;
                #pragma unroll
                for (int c = 0; c < 8; ++c) {
                    float4 hq = hp[c];
                    a  += wa[4*c+0]*hq.x + wa[4*c+1]*hq.y
                        + wa[4*c+2]*hq.z + wa[4*c+3]*hq.w;
                    bb += wb[4*c+0]*hq.x + wb[4*c+1]*hq.y
                        + wb[4*c+2]*hq.z + wb[4*c+3]*hq.w;
                }
                float ax = __shfl_xor(a, 32);
                float bx = __shfl_xor(bb, 32);
                float full = (lane < 32) ? (a + ax) : (bb + bx);
                ltc_sh[s][lane] = fast_tanh(full + sA);
            }
        }
    } else {
        // ================= role 3: attention + online softmax =================
        float w[32];
        const int r  = lane & 31;
        const int hb = lane & 32;
        #pragma unroll
        for (int j = 0; j < 32; ++j) w[j] = at_w1[r*64 + hb + j];
        const float sA = at_b1[r];
        const float sB = at_w2[r];
        const float sC = at_b2[0];
        float m_run = -1.0e30f, s_run = 0.0f, c_run = 0.0f;

        for (int i = 0; i < NIT; ++i) {
            BAR();
            const int t3 = i - 6;
            if (t3 >= 0 && t3 < T_) {
                const int s = t3 & 1;
                float lt = ltc_sh[s][lane];
                const float4* lp = (const float4*)(ltc_sh[s] + hb);
                float acc = 0.0f;
                #pragma unroll
                for (int c = 0; c < 8; ++c) {
                    float4 lq = lp[c];
                    acc += w[4*c+0]*lq.x + w[4*c+1]*lq.y
                         + w[4*c+2]*lq.z + w[4*c+3]*lq.w;
                }
                acc += __shfl_xor(acc, 32);
                float a1 = fast_tanh(acc + sA);
                float v  = a1 * sB;
                v += __shfl_xor(v, 1);  v += __shfl_xor(v, 2);
                v += __shfl_xor(v, 4);  v += __shfl_xor(v, 8);
                v += __shfl_xor(v, 16);
                float logit = v + sC;
                float mn = fmaxf(m_run, logit);
                float e1 = fexp2((m_run - mn) * L2E);
                float p  = fexp2((logit - mn) * L2E);
                s_run = s_run * e1 + p;
                c_run = c_run * e1 + p * lt;
                m_run = mn;
            }
        }
        ctx_sh[lane] = c_run * frcp(s_run);
    }

    // ---------------- epilogue: heads ----------------
    BAR();

    if (wid == 0) {
        // depths head: Linear(64->64)+relu, Linear(64->5)
        float r1 = d_b1[lane];
        #pragma unroll
        for (int c = 0; c < 16; ++c) {
            float4 cq = ((const float4*)ctx_sh)[c];
            float4 wq = ((const float4*)(d_w1 + lane*64))[c];
            r1 += wq.x*cq.x + wq.y*cq.y + wq.z*cq.z + wq.w*cq.w;
        }
        r1 = fmaxf(r1, 0.0f);
        #pragma unroll
        for (int k = 0; k < 5; ++k) {
            float v = d_w2[k*64 + lane] * r1;
            v += __shfl_xor(v, 1);  v += __shfl_xor(v, 2);
            v += __shfl_xor(v, 4);  v += __shfl_xor(v, 8);
            v += __shfl_xor(v, 16); v += __shfl_xor(v, 32);
            if (lane == 0) out[b*5 + k] = v + d_b2[k];
        }
    } else if (wid == 1) {
        // overflow head: 64->64 relu, 64->32 relu, 32->1 sigmoid
        float r1 = o_b1[lane];
        #pragma unroll
        for (int c = 0; c < 16; ++c) {
            float4 cq = ((const float4*)ctx_sh)[c];
            float4 wq = ((const float4*)(o_w1 + lane*64))[c];
            r1 += wq.x*cq.x + wq.y*cq.y + wq.z*cq.z + wq.w*cq.w;
        }
        r1 = fmaxf(r1, 0.0f);
        const int r  = lane & 31;
        const int hb = lane & 32;
        float acc = 0.0f;
        #pragma unroll
        for (int j = 0; j < 32; ++j) {
            float rj = __shfl(r1, hb + j);
            acc += o_w2[r*64 + hb + j] * rj;
        }
        acc += __shfl_xor(acc, 32);
        float r2 = fmaxf(acc + o_b2[r], 0.0f);
        float v  = o_w3[r] * r2;
        v += __shfl_xor(v, 1);  v += __shfl_xor(v, 2);
        v += __shfl_xor(v, 4);  v += __shfl_xor(v, 8);
        v += __shfl_xor(v, 16);
        if (lane == 0) out[5*B + b] = fast_sigmoid(v + o_b3[0]);
    } else if (wid == 2) {
        // intensity head: 64->32 relu, 32->1 sigmoid
        const int r  = lane & 31;
        const int hb = lane & 32;
        float acc = 0.0f;
        #pragma unroll
        for (int c = 0; c < 8; ++c) {
            float4 cq = ((const float4*)(ctx_sh + hb))[c];
            float4 wq = ((const float4*)(i_w1 + r*64 + hb))[c];
            acc += wq.x*cq.x + wq.y*cq.y + wq.z*cq.z + wq.w*cq.w;
        }
        acc += __shfl_xor(acc, 32);
        float r1 = fmaxf(acc + i_b1[r], 0.0f);
        float v  = i_w2[r] * r1;
        v += __shfl_xor(v, 1);  v += __shfl_xor(v, 2);
        v += __shfl_xor(v, 4);  v += __shfl_xor(v, 8);
        v += __shfl_xor(v, 16);
        if (lane == 0) out[6*B + b] = fast_sigmoid(v + i_b2[0]);
    }
}

extern "C" void kernel_launch(void* const* d_in, const int* in_sizes, int n_in,
                              void* d_out, int out_size, void* d_ws, size_t ws_size,
                              hipStream_t stream) {
    (void)n_in; (void)out_size; (void)d_ws; (void)ws_size;
    const float* X     = (const float*)d_in[0];
    const float* fg_w1 = (const float*)d_in[1];
    const float* fg_b1 = (const float*)d_in[2];
    const float* fg_w2 = (const float*)d_in[3];
    const float* fg_b2 = (const float*)d_in[4];
    const float* fwin  = (const float*)d_in[5];
    const float* fbin  = (const float*)d_in[6];
    const float* fwrec = (const float*)d_in[7];
    const float* swin  = (const float*)d_in[8];
    const float* sbin  = (const float*)d_in[9];
    const float* swrec = (const float*)d_in[10];
    const float* fu_w  = (const float*)d_in[11];
    const float* fu_b  = (const float*)d_in[12];
    const float* at_w1 = (const float*)d_in[13];
    const float* at_b1 = (const float*)d_in[14];
    const float* at_w2 = (const float*)d_in[15];
    const float* at_b2 = (const float*)d_in[16];
    const float* d_w1  = (const float*)d_in[17];
    const float* d_b1  = (const float*)d_in[18];
    const float* d_w2  = (const float*)d_in[19];
    const float* d_b2  = (const float*)d_in[20];
    const float* o_w1  = (const float*)d_in[21];
    const float* o_b1  = (const float*)d_in[22];
    const float* o_w2  = (const float*)d_in[23];
    const float* o_b2  = (const float*)d_in[24];
    const float* o_w3  = (const float*)d_in[25];
    const float* o_b3  = (const float*)d_in[26];
    const float* i_w1  = (const float*)d_in[27];
    const float* i_b1  = (const float*)d_in[28];
    const float* i_w2  = (const float*)d_in[29];
    const float* i_b2  = (const float*)d_in[30];
    float* out = (float*)d_out;

    const int B = in_sizes[0] / (T_ * D_);
    dim3 grid(B), block(256);
    hipLaunchKernelGGL(lnn_fused, grid, block, 0, stream,
        X, fg_w1, fg_b1, fg_w2, fg_b2, fwin, fbin, fwrec, swin, sbin, swrec,
        fu_w, fu_b, at_w1, at_b1, at_w2, at_b2, d_w1, d_b1, d_w2, d_b2,
        o_w1, o_b1, o_w2, o_b2, o_w3, o_b3, i_w1, i_b1, i_w2, i_b2, out, B);
}